// Round 4
// baseline (39263.535 us; speedup 1.0000x reference)
//
#include <hip/hip_runtime.h>
#include <math.h>

// VNETDetector: bitwise-faithful reproduction of the numpy f32 reference.
//
// Why bitwise: the Viterbi path metric grows to ~2e5 (llr>=0, never
// renormalized), so f32 ulp there is ~0.01-0.03. The argmin decisions are
// sensitive at exactly that scale: ANY restructuring of the scan arithmetic
// (blocked min-plus, f64, reassociation) perturbs the state profile by
// O(ulp*sqrt(merge_window)) and flips hundreds of bits vs the f32-sequential
// reference. Threshold 2e-2 on {0,1} bits allows ZERO flips. Hence:
//  - k1_mlp: llrs in f32 replicating numpy op order: h = relu(fl(fl(x*W1)+b1))
//    (matmul (T,1)@(1,100) is a single mul; +b1 is a separate add); logits =
//    ascending-k FMA from 0 (OpenBLAS sgemm microkernel order), then +b2;
//    log_softmax = (x - max) - log(S), S = numpy pairwise-16 sum of exps;
//    exp/log evaluated in f64 and rounded to f32 (≈correctly-rounded f32).
//    __fmul_rn/__fadd_rn/__fsub_rn everywhere to prevent fp-contraction.
//  - k2_scan: the trellis, sequential and bitwise-f32: path=fl(v+llr),
//    v'=min over the 2 incoming edges, bit = first-occurrence argmin parity
//    BEFORE the update. 8-state collapse (trans rows i and i+8 identical =>
//    v16[i]==v16[i+8] bitwise; argmin parity preserved with index-order tie
//    handling). Single wave, all 64 lanes replicate the state vector
//    (no cross-lane on the critical path); llrs staged per-64-step tile
//    global->LDS with one-tile lookahead; lane j emits bit j of each tile.
//  - All scratch in static __device__ arrays (d_ws untouched).
//  - Runtime dtype detect (f32 vs bf16-converted dataset) from W1 bit
//    patterns; all I/O branched on the (wave-uniform) flag.

#define T_LEN 250000
#define HID   100
#define NB    3907            // ceil(T_LEN/64); last tile has 16 steps
#define NTILE 3908            // padded tile count for safe staging reads

static __device__ float g_llr[NTILE * 1024];   // [t][s] f32 llrs, tile-padded (16 MB)
static __device__ int   g_isf32;               // 1 = f32 data, 0 = bf16 data

// Template-named symbol kept in case the build system expects it. Never launched
// with parameters; harmless.
__global__ void VNETDetector_3942779978170_kernel() {}

// ---- dtype-branched I/O helpers (flag wave-uniform; no divergence) --------
__device__ __forceinline__ float ld_in(const void* p, long i, int f32) {
    if (f32) return ((const float*)p)[i];
    unsigned w = (unsigned)((const unsigned short*)p)[i] << 16;
    return __uint_as_float(w);
}
__device__ __forceinline__ void st_out(void* p, long i, float v, int f32) {
    if (f32) { ((float*)p)[i] = v; return; }
    unsigned u = __float_as_uint(v);                       // RNE f32 -> bf16
    ((unsigned short*)p)[i] = (unsigned short)((u + 0x7FFFu + ((u >> 16) & 1u)) >> 16);
}

// ---- k0: detect input dtype from W1 (N(0,1)) bit patterns -----------------
// bf16 view of f32 data: the low-half uint16s have uniform random "exponent"
// fields (~84% outside [100,140]); genuine N(0,1) bf16 exponents are always
// inside. One thread, 64 halves, count outliers.
__global__ void k0_detect(const unsigned short* __restrict__ w1u) {
    if (threadIdx.x != 0) return;
    int outliers = 0;
    for (int k = 0; k < 64; k++) {
        int e = (w1u[k] >> 7) & 0xFF;
        outliers += (e < 100 || e > 140) ? 1 : 0;
    }
    g_isf32 = (outliers >= 8) ? 1 : 0;
}

// ---- k1: f32 MLP + log_softmax in numpy op order -> g_llr + outputs 1,2 ---
__global__ __launch_bounds__(256) void k1_mlp(
        const void* __restrict__ rx, const void* __restrict__ W1,
        const void* __restrict__ b1, const void* __restrict__ W2,
        const void* __restrict__ b2, void* __restrict__ out)
{
    __shared__ float w1s[HID], b1s[HID], w2s[HID * 16], b2s[16];
    int f32 = g_isf32;
    for (int i = threadIdx.x; i < HID; i += 256) {
        w1s[i] = ld_in(W1, i, f32);
        b1s[i] = ld_in(b1, i, f32);
    }
    for (int i = threadIdx.x; i < HID * 16; i += 256) {
        int j = i >> 4, s = i & 15;            // j-major storage
        w2s[i] = ld_in(W2, s * HID + j, f32);  // W2 is [16,100] row-major
    }
    if (threadIdx.x < 16) b2s[threadIdx.x] = ld_in(b2, threadIdx.x, f32);
    __syncthreads();

    int t = blockIdx.x * 256 + threadIdx.x;
    if (t >= T_LEN) return;
    float x = ld_in(rx, t, f32);

    // logits: sgemm-order ascending-k FMA from 0; bias added afterwards
    float acc[16];
#pragma unroll
    for (int s = 0; s < 16; s++) acc[s] = 0.0f;
    for (int j = 0; j < HID; j++) {
        float h = __fmul_rn(x, w1s[j]);        // (T,1)@(1,100): single mul
        h = __fadd_rn(h, b1s[j]);              // separate bias add
        h = h > 0.0f ? h : 0.0f;               // relu
        const float* w = &w2s[j * 16];
#pragma unroll
        for (int s = 0; s < 16; s++) acc[s] = fmaf(h, w[s], acc[s]);
    }
    float logits[16];
#pragma unroll
    for (int s = 0; s < 16; s++) logits[s] = __fadd_rn(acc[s], b2s[s]);

    // log_softmax: (x - m) - log(sum(exp(x - m))), numpy pairwise-16 sum
    float m = logits[0];
#pragma unroll
    for (int s = 1; s < 16; s++) m = fmaxf(m, logits[s]);
    float y[16], e[16];
#pragma unroll
    for (int s = 0; s < 16; s++) {
        y[s] = __fsub_rn(logits[s], m);
        e[s] = (float)exp((double)y[s]);       // ~correctly-rounded f32 exp
    }
    float r[8];
#pragma unroll
    for (int j = 0; j < 8; j++) r[j] = __fadd_rn(e[j], e[j + 8]);
    float s01 = __fadd_rn(r[0], r[1]), s23 = __fadd_rn(r[2], r[3]);
    float s45 = __fadd_rn(r[4], r[5]), s67 = __fadd_rn(r[6], r[7]);
    float S = __fadd_rn(__fadd_rn(s01, s23), __fadd_rn(s45, s67));
    float logS = (float)log((double)S);

    float p[16];
    float* lrow = &g_llr[(long)t * 16];
#pragma unroll
    for (int s = 0; s < 16; s++) {
        float lp = __fsub_rn(y[s], logS);      // log_prob (f32)
        lrow[s] = -lp;                         // llr (exact negation)
        p[s] = (float)exp((double)lp);         // probs (f32)
    }
    float best = p[0]; int bi = 0;
#pragma unroll
    for (int s = 1; s < 16; s++)
        if (p[s] > best) { best = p[s]; bi = s; }   // first-occurrence argmax
    st_out(out, (long)T_LEN + t,     (float)(bi & 1), f32);
    st_out(out, 2L * T_LEN + t,      best,            f32);
}

// ---- k2: bitwise-f32 sequential trellis, single wave ----------------------
__global__ __launch_bounds__(64) void k2_scan(void* __restrict__ out)
{
    __shared__ float tile[2][1024];            // two 64-step llr tiles
    int f32 = g_isf32;
    int lane = threadIdx.x;
    const float4* g4 = (const float4*)g_llr;

    // stage tile 0 -> LDS[0]; preload tile 1 into regs
    float4 pre[4];
#pragma unroll
    for (int r = 0; r < 4; r++) pre[r] = g4[r * 64 + lane];
#pragma unroll
    for (int r = 0; r < 4; r++) ((float4*)tile[0])[r * 64 + lane] = pre[r];
#pragma unroll
    for (int r = 0; r < 4; r++) pre[r] = g4[256 + r * 64 + lane];

    float v[8];
#pragma unroll
    for (int k = 0; k < 8; k++) v[k] = 0.0f;

    for (int tb = 0; tb < NB; tb++) {
        int buf = tb & 1;
        int nst = (tb == NB - 1) ? 16 : 64;
        const float4* lt = (const float4*)tile[buf];
        unsigned long long mask = 0;

        float4 c0 = lt[0], c1 = lt[1], c2 = lt[2], c3 = lt[3];
        for (int s = 0; s < nst; s++) {
            // prefetch next step's llrs
            float4 n0, n1, n2, n3;
            if (s + 1 < nst) {
                n0 = lt[(s + 1) * 4 + 0]; n1 = lt[(s + 1) * 4 + 1];
                n2 = lt[(s + 1) * 4 + 2]; n3 = lt[(s + 1) * 4 + 3];
            }
            // bit BEFORE update: first-occurrence argmin parity over v16
            // (= over v8 since v16[i]=v8[i&7]); inter-class exact ties
            // resolved by lowest index (rare, wave-uniform branch).
            float mE = fminf(fminf(v[0], v[2]), fminf(v[4], v[6]));
            float mO = fminf(fminf(v[1], v[3]), fminf(v[5], v[7]));
            int bit;
            if (mO != mE) {
                bit = (mO < mE) ? 1 : 0;
            } else {
                float m8 = mE;
                int mk = (v[0] == m8 ? 1 : 0)   | (v[1] == m8 ? 2 : 0)
                       | (v[2] == m8 ? 4 : 0)   | (v[3] == m8 ? 8 : 0)
                       | (v[4] == m8 ? 16 : 0)  | (v[5] == m8 ? 32 : 0)
                       | (v[6] == m8 ? 64 : 0)  | (v[7] == m8 ? 128 : 0);
                bit = ((mk & (-mk)) & 0xAA) ? 1 : 0;   // parity of lowest attainer
            }
            mask |= (unsigned long long)bit << s;

            // f32-exact update: path[j] = fl(v[j&7]+llr[j]); v'[k]=min(path[2k],path[2k+1])
            float l[16] = { c0.x, c0.y, c0.z, c0.w, c1.x, c1.y, c1.z, c1.w,
                            c2.x, c2.y, c2.z, c2.w, c3.x, c3.y, c3.z, c3.w };
            float pth[16];
#pragma unroll
            for (int j = 0; j < 16; j++) pth[j] = __fadd_rn(v[j & 7], l[j]);
#pragma unroll
            for (int k = 0; k < 8; k++) v[k] = fminf(pth[2 * k], pth[2 * k + 1]);

            c0 = n0; c1 = n1; c2 = n2; c3 = n3;
        }

        // lane j emits bit j of this tile (mask is lane-uniform)
        long t0 = (long)tb * 64;
        if (lane < nst)
            st_out(out, t0 + lane, (float)((mask >> lane) & 1ULL), f32);

        // stage preloaded tile tb+1 into the other buffer; preload tb+2
        if (tb + 1 < NB) {
#pragma unroll
            for (int r = 0; r < 4; r++)
                ((float4*)tile[buf ^ 1])[r * 64 + lane] = pre[r];
            int nx = (tb + 2 < NB) ? (tb + 2) : (NB - 1);   // clamped (padded array)
#pragma unroll
            for (int r = 0; r < 4; r++)
                pre[r] = g4[(long)nx * 256 + r * 64 + lane];
        }
    }
}

extern "C" void kernel_launch(void* const* d_in, const int* in_sizes, int n_in,
                              void* d_out, int out_size, void* d_ws, size_t ws_size,
                              hipStream_t stream)
{
    const void* rx = d_in[0];
    const void* W1 = d_in[1];
    const void* b1 = d_in[2];
    const void* W2 = d_in[3];
    const void* b2 = d_in[4];
    // d_out: [0,T) detected_word, [T,2T) confident_bits, [2T,3T) confidence
    // d_ws: intentionally unused (all scratch is static __device__).

    k0_detect<<<1,   64,  0, stream>>>((const unsigned short*)W1);
    k1_mlp   <<<977, 256, 0, stream>>>(rx, W1, b1, W2, b2, d_out);
    k2_scan  <<<1,   64,  0, stream>>>(d_out);
}